// Round 7
// baseline (691.060 us; speedup 1.0000x reference)
//
#include <hip/hip_runtime.h>
#include <hip/hip_bf16.h>

// adLIF: Wx = x @ W^T (fp32 FMA GEMM, strictly sequential-K accumulation to
// mirror BLAS bit-for-bit), then sequential LIF scan over T with rounding-exact
// fp32 ops. Input dtype (fp32 vs bf16) detected ON DEVICE from x's bit pattern.
// r17 GEMM: r6 structure VERBATIM (VGPR 116, 418 us, cached C-stores).
//   Ledger: dbuf r11 (VGPR 200, 620), dbuf r15 (VGPR 144, 555) -> no dbuf ever;
//   keep VGPR <= 128. GEMM is LDS-read-issue-bound (~4 ds_read_b128/thread/k);
//   418 us ~= 80% of that pipe's ceiling.
// r17 scan: LDS-RESIDENT WHOLE SEQUENCE. Ledger evidence: every mixed-stream
//   scan ran at ~1 memory latency per timestep (138-213 us), anti-correlated
//   with preceding GEMM speed (L3-residency lottery: 270 ns/step after slow
//   GEMMs, 389 ns/step after fast ones). Fix: separate phases. 128 KB LDS
//   holds Wx[512t][64h] (m201 precedent for 128KB blocks). Phase 1: all 4
//   waves bulk-copy global->LDS (pure memcpy pattern -> pipelines to BW).
//   Phase 2: wave 0 runs the 512-step recurrence from LDS (8-row read-ahead,
//   2 lanes/bank = conflict-free), spikes in place. Phase 3: all waves bulk-
//   store x4-packed. Deterministic ~50-80 us; no L3 luck, no latency chain.

#define M_SZ 65536  // B*T
#define H_SZ 512
#define K_SZ 512
#define B_SZ 128
#define T_SZ 512
#define LSTR 132  // LDS row stride (dwords), %32==4: staging writes conflict-free

typedef __attribute__((ext_vector_type(4))) float f32x4;
typedef __attribute__((ext_vector_type(4))) unsigned int u32x4;

__device__ __forceinline__ bool detect_bf16(const unsigned int* __restrict__ w) {
  int c = 0;
#pragma unroll
  for (int i = 0; i < 64; ++i) {
    unsigned int e = (w[i] >> 7) & 0xffu;
    c += (e >= 115u && e <= 131u) ? 1 : 0;
  }
  return c > 32;  // bf16 exponents cluster in [115,131]; fp32 mantissa bits don't
}

template <bool ISB>
__device__ __forceinline__ f32x4 ld4t(const void* __restrict__ p, size_t off) {
  if constexpr (!ISB) {
    return *reinterpret_cast<const f32x4*>(reinterpret_cast<const float*>(p) + off);
  } else {
    uint2 v = *reinterpret_cast<const uint2*>(reinterpret_cast<const unsigned short*>(p) + off);
    f32x4 r;
    r.x = __uint_as_float((v.x & 0xffffu) << 16);
    r.y = __uint_as_float(v.x & 0xffff0000u);
    r.z = __uint_as_float((v.y & 0xffffu) << 16);
    r.w = __uint_as_float(v.y & 0xffff0000u);
    return r;
  }
}

template <bool ISB>
__device__ __forceinline__ float ld1t(const void* __restrict__ p, int i) {
  if constexpr (!ISB) return reinterpret_cast<const float*>(p)[i];
  return __uint_as_float((unsigned int)(reinterpret_cast<const unsigned short*>(p)[i]) << 16);
}

// ---------------- GEMM: C[m][n] = sum_k X[m][k]*W[n][k], fp32, k ascending ----
template <bool ISB>
__device__ __forceinline__ void gemm_body(const void* __restrict__ X,
                                          const void* __restrict__ Wm,
                                          float* __restrict__ C,
                                          float* __restrict__ As,
                                          float* __restrict__ Bs) {
  const int tid = threadIdx.x;
  const int r0 = tid >> 2;       // 0..63: staged row
  const int q0 = (tid & 3) * 4;  // 0,4,8,12: k-group
  const int tx = tid & 15;       // n-group
  const int ty = tid >> 4;       // m-group
  const size_t M0 = (size_t)(blockIdx.x >> 2) * 128;
  const int N0 = (blockIdx.x & 3) * 128;

  float acc[8][8];
#pragma unroll
  for (int i = 0; i < 8; ++i)
#pragma unroll
    for (int j = 0; j < 8; ++j) acc[i][j] = 0.0f;

  const size_t aoff0 = (M0 + r0) * K_SZ + q0;
  const size_t aoff1 = (M0 + r0 + 64) * K_SZ + q0;
  const size_t boff0 = (size_t)(N0 + r0) * K_SZ + q0;
  const size_t boff1 = (size_t)(N0 + r0 + 64) * K_SZ + q0;

  f32x4 pa0 = ld4t<ISB>(X, aoff0), pa1 = ld4t<ISB>(X, aoff1);
  f32x4 pb0 = ld4t<ISB>(Wm, boff0), pb1 = ld4t<ISB>(Wm, boff1);

  for (int kk = 0; kk < K_SZ; kk += 16) {
    __syncthreads();  // prior compute done -> LDS free
    As[(q0 + 0) * LSTR + r0] = pa0.x; As[(q0 + 1) * LSTR + r0] = pa0.y;
    As[(q0 + 2) * LSTR + r0] = pa0.z; As[(q0 + 3) * LSTR + r0] = pa0.w;
    As[(q0 + 0) * LSTR + r0 + 64] = pa1.x; As[(q0 + 1) * LSTR + r0 + 64] = pa1.y;
    As[(q0 + 2) * LSTR + r0 + 64] = pa1.z; As[(q0 + 3) * LSTR + r0 + 64] = pa1.w;
    Bs[(q0 + 0) * LSTR + r0] = pb0.x; Bs[(q0 + 1) * LSTR + r0] = pb0.y;
    Bs[(q0 + 2) * LSTR + r0] = pb0.z; Bs[(q0 + 3) * LSTR + r0] = pb0.w;
    Bs[(q0 + 0) * LSTR + r0 + 64] = pb1.x; Bs[(q0 + 1) * LSTR + r0 + 64] = pb1.y;
    Bs[(q0 + 2) * LSTR + r0 + 64] = pb1.z; Bs[(q0 + 3) * LSTR + r0 + 64] = pb1.w;
    __syncthreads();  // tile ready
    if (kk + 16 < K_SZ) {  // prefetch next chunk; in flight across compute
      pa0 = ld4t<ISB>(X, aoff0 + kk + 16); pa1 = ld4t<ISB>(X, aoff1 + kk + 16);
      pb0 = ld4t<ISB>(Wm, boff0 + kk + 16); pb1 = ld4t<ISB>(Wm, boff1 + kk + 16);
    }
#pragma unroll
    for (int k = 0; k < 16; ++k) {
      const f32x4 a0 = *reinterpret_cast<const f32x4*>(As + k * LSTR + ty * 4);
      const f32x4 a1 = *reinterpret_cast<const f32x4*>(As + k * LSTR + 64 + ty * 4);
      const f32x4 b0 = *reinterpret_cast<const f32x4*>(Bs + k * LSTR + tx * 4);
      const f32x4 b1 = *reinterpret_cast<const f32x4*>(Bs + k * LSTR + 64 + tx * 4);
      const float av[8] = {a0.x, a0.y, a0.z, a0.w, a1.x, a1.y, a1.z, a1.w};
      const float bv[8] = {b0.x, b0.y, b0.z, b0.w, b1.x, b1.y, b1.z, b1.w};
#pragma unroll
      for (int i = 0; i < 8; ++i)
#pragma unroll
        for (int j = 0; j < 8; ++j) acc[i][j] += av[i] * bv[j];  // contracts to FMA
    }
  }

#pragma unroll
  for (int r = 0; r < 8; ++r) {
    const size_t m = M0 + ((r < 4) ? (ty * 4 + r) : (64 + ty * 4 + (r - 4)));
    float* Cp = C + m * H_SZ + N0;
    f32x4 v0 = {acc[r][0], acc[r][1], acc[r][2], acc[r][3]};
    f32x4 v1 = {acc[r][4], acc[r][5], acc[r][6], acc[r][7]};
    *reinterpret_cast<f32x4*>(Cp + tx * 4) = v0;
    *reinterpret_cast<f32x4*>(Cp + 64 + tx * 4) = v1;
  }
}

__global__ __launch_bounds__(256) void sgemm_bt(const void* __restrict__ X,
                                                const void* __restrict__ Wm,
                                                float* __restrict__ C) {
  __shared__ float As[16 * LSTR];  // 8.45 KB
  __shared__ float Bs[16 * LSTR];  // 8.45 KB
  if (detect_bf16(reinterpret_cast<const unsigned int*>(X)))
    gemm_body<true>(X, Wm, C, As, Bs);
  else
    gemm_body<false>(X, Wm, C, As, Bs);
}

// ---------------- LIF scan: LDS-resident whole sequence ---------------------
// 1024 blocks x 256 thr (4 waves); block = (b, 64-h strip). LDS wxb[512][64]
// = 128 KB holds the block's entire Wx sequence (1 block/CU, 4 CU-rounds).
// Phase 1: all waves bulk-copy 128 KB global->LDS (32 f32x4/thread in groups
//          of 8 -> memcpy-style pipelining, BW-bound, no dependent consumer).
// Phase 2: wave 0 runs the 512-step recurrence from LDS. ds_read [t][lane]:
//          2 lanes/bank = conflict-free. 8-row read-ahead hides LDS latency;
//          spikes overwrite wxb[t] in place (rows already consumed).
// Phase 3: all waves bulk-store spikes LDS->global, x4 packed (bf16: 2/dword).
template <bool ISB>
__device__ __forceinline__ void scan_body(
    const float* __restrict__ wx, const void* __restrict__ alpha_p,
    const void* __restrict__ beta_p, const void* __restrict__ a_p,
    const void* __restrict__ b_p, const void* __restrict__ u0p,
    const void* __restrict__ w0p, const void* __restrict__ s0p,
    void* __restrict__ out, float* __restrict__ wxb) {
  const int tid = threadIdx.x;
  const int lane = tid & 63;
  const int wid = tid >> 6;
  const int b = blockIdx.x >> 3;
  const int strip = (blockIdx.x & 7);
  const int h = strip * 64 + lane;

  // ---- phase 1: bulk load Wx[b, :, strip*64 .. +64) -> LDS [512][64] ----
  // thread covers rows 16*m + (tid>>4), cols (tid&15)*4, m = 0..31
  {
    const float* gb = wx + (size_t)b * T_SZ * H_SZ + strip * 64 + (tid & 15) * 4;
    const int rb = tid >> 4;  // 0..15
#pragma unroll
    for (int g = 0; g < 4; ++g) {
      f32x4 v[8];
#pragma unroll
      for (int j = 0; j < 8; ++j) {
        const int r = 16 * (g * 8 + j) + rb;
        v[j] = *reinterpret_cast<const f32x4*>(gb + (size_t)r * H_SZ);
      }
#pragma unroll
      for (int j = 0; j < 8; ++j) {
        const int r = 16 * (g * 8 + j) + rb;
        *reinterpret_cast<f32x4*>(wxb + r * 64 + (tid & 15) * 4) = v[j];
      }
    }
  }
  __syncthreads();  // LDS sequence ready

  // ---- phase 2: wave 0 runs the recurrence ----
  if (wid == 0) {
    const float al = fminf(fmaxf(ld1t<ISB>(alpha_p, h), (float)0.8187307530779818),
                           (float)0.9607894391523232);
    const float be = fminf(fmaxf(ld1t<ISB>(beta_p, h), (float)0.9672161004820059),
                           (float)0.9917013044213351);
    const float av = fminf(fmaxf(ld1t<ISB>(a_p, h), -1.0f), 1.0f);
    const float bv = fminf(fmaxf(ld1t<ISB>(b_p, h), 0.0f), 2.0f);
    const float om = __fsub_rn(1.0f, al);
    const int bh = b * H_SZ + h;
    float u = ld1t<ISB>(u0p, bh);
    float w = ld1t<ISB>(w0p, bh);
    float s = ld1t<ISB>(s0p, bh);

    float nxt[8];
#pragma unroll
    for (int j = 0; j < 8; ++j) nxt[j] = wxb[j * 64 + lane];
    for (int t0 = 0; t0 < T_SZ; t0 += 8) {
      float cur8[8];
#pragma unroll
      for (int j = 0; j < 8; ++j) cur8[j] = nxt[j];
      if (t0 + 8 < T_SZ) {  // read ahead next 8 rows (independent ds_reads)
#pragma unroll
        for (int j = 0; j < 8; ++j) nxt[j] = wxb[(t0 + 8 + j) * 64 + lane];
      }
#pragma unroll
      for (int j = 0; j < 8; ++j) {
        // numpy left-to-right, each op individually rounded (no FMA contraction)
        w = __fadd_rn(__fadd_rn(__fmul_rn(be, w), __fmul_rn(av, u)), __fmul_rn(bv, s));
        u = __fadd_rn(__fmul_rn(al, __fsub_rn(u, s)), __fmul_rn(om, __fsub_rn(cur8[j], w)));
        s = (u > 1.0f) ? 1.0f : 0.0f;
        wxb[(t0 + j) * 64 + lane] = s;  // in place; row consumed (read-ahead < write+8)
      }
    }
  }
  __syncthreads();  // spikes ready in LDS

  // ---- phase 3: bulk store spikes LDS -> out [b][t][h] ----
  if constexpr (!ISB) {
    float* outf = reinterpret_cast<float*>(out) + (size_t)b * T_SZ * H_SZ + strip * 64;
    const int rb = tid >> 4;
#pragma unroll
    for (int m = 0; m < 32; ++m) {
      const int r = 16 * m + rb;
      const f32x4 v = *reinterpret_cast<const f32x4*>(wxb + r * 64 + (tid & 15) * 4);
      *reinterpret_cast<f32x4*>(outf + (size_t)r * H_SZ + (tid & 15) * 4) = v;
    }
  } else {
    // bf16: pack 2 spikes/dword (1.0f -> 0x3F80, 0.0f -> 0 by exact truncation)
    unsigned short* outu =
        reinterpret_cast<unsigned short*>(out) + (size_t)b * T_SZ * H_SZ + strip * 64;
    const int rb = tid >> 3;       // 0..31
    const int h0 = (tid & 7) * 8;  // 8 h per thread
#pragma unroll
    for (int m = 0; m < 16; ++m) {
      const int r = 32 * m + rb;
      const f32x4 f0 = *reinterpret_cast<const f32x4*>(wxb + r * 64 + h0);
      const f32x4 f1 = *reinterpret_cast<const f32x4*>(wxb + r * 64 + h0 + 4);
      u32x4 d;
      d.x = (__float_as_uint(f0.y) & 0xffff0000u) | (__float_as_uint(f0.x) >> 16);
      d.y = (__float_as_uint(f0.w) & 0xffff0000u) | (__float_as_uint(f0.z) >> 16);
      d.z = (__float_as_uint(f1.y) & 0xffff0000u) | (__float_as_uint(f1.x) >> 16);
      d.w = (__float_as_uint(f1.w) & 0xffff0000u) | (__float_as_uint(f1.z) >> 16);
      *reinterpret_cast<u32x4*>(outu + (size_t)r * H_SZ + h0) = d;
    }
  }
}

__global__ __launch_bounds__(256) void lif_scan(
    const float* __restrict__ wx, const void* __restrict__ X,
    const void* __restrict__ alpha_p, const void* __restrict__ beta_p,
    const void* __restrict__ a_p, const void* __restrict__ b_p,
    const void* __restrict__ u0p, const void* __restrict__ w0p,
    const void* __restrict__ s0p, void* __restrict__ out) {
  __shared__ float wxb[T_SZ * 64];  // 128 KB (gfx950 LDS 160 KB; m201 precedent)
  if (detect_bf16(reinterpret_cast<const unsigned int*>(X)))
    scan_body<true>(wx, alpha_p, beta_p, a_p, b_p, u0p, w0p, s0p, out, wxb);
  else
    scan_body<false>(wx, alpha_p, beta_p, a_p, b_p, u0p, w0p, s0p, out, wxb);
}

extern "C" void kernel_launch(void* const* d_in, const int* in_sizes, int n_in,
                              void* d_out, int out_size, void* d_ws, size_t ws_size,
                              hipStream_t stream) {
  const void* X = d_in[0];   // x [B,T,I]
  const void* Wm = d_in[1];  // W [H,I]
  float* ws = reinterpret_cast<float*>(d_ws);  // Wx fp32 [B,T,H]

  sgemm_bt<<<dim3((M_SZ / 128) * (H_SZ / 128)), dim3(256), 0, stream>>>(X, Wm, ws);

  lif_scan<<<dim3(B_SZ * 8), dim3(256), 0, stream>>>(
      ws, X, d_in[2], d_in[3], d_in[4], d_in[5], d_in[6], d_in[7], d_in[8], d_out);
}

// Round 8
// 688.770 us; speedup vs baseline: 1.0033x; 1.0033x over previous
//
#include <hip/hip_runtime.h>
#include <hip/hip_bf16.h>

// adLIF FUSED: one kernel computes Wx = x@W^T tile-by-tile (r6 fp32 FMA GEMM
// body VERBATIM per M-tile -> bit-exact k-order) and runs the LIF scan over
// each tile's 128 timesteps IN REGISTERS before moving on. Wx never touches
// HBM (r0-r17 evidence: the standalone scan is latency-bound at 140-270 us
// because B*H/64 = 1024 waves can't cover HBM latency for 134 MB; fusion
// removes 268 MB of round-trip traffic and the whole latency-bound kernel).
// Block = (b, 128-h strip): 512 blocks = 2/CU (grid-limited occupancy ->
// immune to the 128-VGPR cliff up to 256). Per block: 4 M-tiles (t-slices);
// per tile: k-loop (64 barriers, unchanged) + 32 scan phases (32 barriers).
// Phase p: t_local = 4p+rr for rr=0..3, owned by ty quarter (p&15) using
// acc[rr] (p<16) or acc[4+rr] (p>=16) -- static acc indices, no scratch.
// u/w/s state per h-column lives in LDS (128 floats each); clamped params
// cached in LDS. Spikes stored as coalesced f32x4 (fp32) / packed 4x bf16.
// Input dtype (fp32 vs bf16) detected on device from x's bit pattern.

#define M_SZ 65536  // B*T
#define H_SZ 512
#define K_SZ 512
#define B_SZ 128
#define T_SZ 512
#define LSTR 132  // LDS row stride (dwords), %32==4: staging writes conflict-free

typedef __attribute__((ext_vector_type(4))) float f32x4;

__device__ __forceinline__ bool detect_bf16(const unsigned int* __restrict__ w) {
  int c = 0;
#pragma unroll
  for (int i = 0; i < 64; ++i) {
    unsigned int e = (w[i] >> 7) & 0xffu;
    c += (e >= 115u && e <= 131u) ? 1 : 0;
  }
  return c > 32;  // bf16 exponents cluster in [115,131]; fp32 mantissa bits don't
}

template <bool ISB>
__device__ __forceinline__ f32x4 ld4t(const void* __restrict__ p, size_t off) {
  if constexpr (!ISB) {
    return *reinterpret_cast<const f32x4*>(reinterpret_cast<const float*>(p) + off);
  } else {
    uint2 v = *reinterpret_cast<const uint2*>(reinterpret_cast<const unsigned short*>(p) + off);
    f32x4 r;
    r.x = __uint_as_float((v.x & 0xffffu) << 16);
    r.y = __uint_as_float(v.x & 0xffff0000u);
    r.z = __uint_as_float((v.y & 0xffffu) << 16);
    r.w = __uint_as_float(v.y & 0xffff0000u);
    return r;
  }
}

template <bool ISB>
__device__ __forceinline__ float ld1t(const void* __restrict__ p, int i) {
  if constexpr (!ISB) return reinterpret_cast<const float*>(p)[i];
  return __uint_as_float((unsigned int)(reinterpret_cast<const unsigned short*>(p)[i]) << 16);
}

// ---------------- fused GEMM + scan body ------------------------------------
template <bool ISB>
__device__ __forceinline__ void fused_body(
    const void* __restrict__ X, const void* __restrict__ Wm,
    const void* __restrict__ alpha_p, const void* __restrict__ beta_p,
    const void* __restrict__ a_p, const void* __restrict__ b_p,
    const void* __restrict__ u0p, const void* __restrict__ w0p,
    const void* __restrict__ s0p, void* __restrict__ out,
    float* __restrict__ As, float* __restrict__ Bs, float* __restrict__ st) {
  const int tid = threadIdx.x;
  const int r0 = tid >> 2;       // 0..63: staged row
  const int q0 = (tid & 3) * 4;  // 0,4,8,12: k-group
  const int tx = tid & 15;       // n-group
  const int ty = tid >> 4;       // m-group
  const int b = blockIdx.x >> 2;
  const int N0 = (blockIdx.x & 3) * 128;

  // LDS state: su sw ss | pal pbe pav pbv pom, each [128] indexed by n = h-N0
  float* su = st;        float* sw = st + 128;  float* ss = st + 256;
  float* pal = st + 384; float* pbe = st + 512; float* pav = st + 640;
  float* pbv = st + 768; float* pom = st + 896;

  if (tid < 128) {  // init params (clamped) + initial state for column n = tid
    const int h = N0 + tid;
    const float al = fminf(fmaxf(ld1t<ISB>(alpha_p, h), (float)0.8187307530779818),
                           (float)0.9607894391523232);
    const float be = fminf(fmaxf(ld1t<ISB>(beta_p, h), (float)0.9672161004820059),
                           (float)0.9917013044213351);
    pal[tid] = al;
    pbe[tid] = be;
    pav[tid] = fminf(fmaxf(ld1t<ISB>(a_p, h), -1.0f), 1.0f);
    pbv[tid] = fminf(fmaxf(ld1t<ISB>(b_p, h), 0.0f), 2.0f);
    pom[tid] = __fsub_rn(1.0f, al);
    const int bh = b * H_SZ + h;
    su[tid] = ld1t<ISB>(u0p, bh);
    sw[tid] = ld1t<ISB>(w0p, bh);
    ss[tid] = ld1t<ISB>(s0p, bh);
  }
  // visibility: first k-loop barrier below covers it (st not read until scan)

  float* outf = reinterpret_cast<float*>(out);
  unsigned int* outu = reinterpret_cast<unsigned int*>(out);

  for (int tt = 0; tt < 4; ++tt) {  // M-tile = 128 consecutive t of batch b
    const size_t M0 = (size_t)b * T_SZ + tt * 128;

    float acc[8][8];
#pragma unroll
    for (int i = 0; i < 8; ++i)
#pragma unroll
      for (int j = 0; j < 8; ++j) acc[i][j] = 0.0f;

    const size_t aoff0 = (M0 + r0) * K_SZ + q0;
    const size_t aoff1 = (M0 + r0 + 64) * K_SZ + q0;
    const size_t boff0 = (size_t)(N0 + r0) * K_SZ + q0;
    const size_t boff1 = (size_t)(N0 + r0 + 64) * K_SZ + q0;

    f32x4 pa0 = ld4t<ISB>(X, aoff0), pa1 = ld4t<ISB>(X, aoff1);
    f32x4 pb0 = ld4t<ISB>(Wm, boff0), pb1 = ld4t<ISB>(Wm, boff1);

    for (int kk = 0; kk < K_SZ; kk += 16) {  // r6 k-loop VERBATIM
      __syncthreads();  // prior compute done -> LDS free
      As[(q0 + 0) * LSTR + r0] = pa0.x; As[(q0 + 1) * LSTR + r0] = pa0.y;
      As[(q0 + 2) * LSTR + r0] = pa0.z; As[(q0 + 3) * LSTR + r0] = pa0.w;
      As[(q0 + 0) * LSTR + r0 + 64] = pa1.x; As[(q0 + 1) * LSTR + r0 + 64] = pa1.y;
      As[(q0 + 2) * LSTR + r0 + 64] = pa1.z; As[(q0 + 3) * LSTR + r0 + 64] = pa1.w;
      Bs[(q0 + 0) * LSTR + r0] = pb0.x; Bs[(q0 + 1) * LSTR + r0] = pb0.y;
      Bs[(q0 + 2) * LSTR + r0] = pb0.z; Bs[(q0 + 3) * LSTR + r0] = pb0.w;
      Bs[(q0 + 0) * LSTR + r0 + 64] = pb1.x; Bs[(q0 + 1) * LSTR + r0 + 64] = pb1.y;
      Bs[(q0 + 2) * LSTR + r0 + 64] = pb1.z; Bs[(q0 + 3) * LSTR + r0 + 64] = pb1.w;
      __syncthreads();  // tile ready
      if (kk + 16 < K_SZ) {
        pa0 = ld4t<ISB>(X, aoff0 + kk + 16); pa1 = ld4t<ISB>(X, aoff1 + kk + 16);
        pb0 = ld4t<ISB>(Wm, boff0 + kk + 16); pb1 = ld4t<ISB>(Wm, boff1 + kk + 16);
      }
#pragma unroll
      for (int k = 0; k < 16; ++k) {
        const f32x4 a0 = *reinterpret_cast<const f32x4*>(As + k * LSTR + ty * 4);
        const f32x4 a1 = *reinterpret_cast<const f32x4*>(As + k * LSTR + 64 + ty * 4);
        const f32x4 b0 = *reinterpret_cast<const f32x4*>(Bs + k * LSTR + tx * 4);
        const f32x4 b1 = *reinterpret_cast<const f32x4*>(Bs + k * LSTR + 64 + tx * 4);
        const float av[8] = {a0.x, a0.y, a0.z, a0.w, a1.x, a1.y, a1.z, a1.w};
        const float bv[8] = {b0.x, b0.y, b0.z, b0.w, b1.x, b1.y, b1.z, b1.w};
#pragma unroll
        for (int i = 0; i < 8; ++i)
#pragma unroll
          for (int j = 0; j < 8; ++j) acc[i][j] += av[i] * bv[j];  // contracts to FMA
      }
    }
    // acc[r][j] = Wx[t_local = (r<4 ? ty*4+r : 64+ty*4+r-4)][n = (j<4 ? tx*4+j
    // : 64+tx*4+j-4)] for this tile. Scan phases walk t in order.

    // ---- scan: 32 phases, phase p covers t_local = 4p..4p+3 ----
    for (int p = 0; p < 32; ++p) {
      const bool act = (p < 16) ? (ty == p) : (ty == p - 16);
      if (act) {
        float spkA[4][4];  // [rr][jj]   cols tx*4+jj
        float spkB[4][4];  // [rr][jj]   cols 64+tx*4+jj
#pragma unroll
        for (int jj = 0; jj < 8; ++jj) {
          const int n = (jj < 4) ? (tx * 4 + jj) : (64 + tx * 4 + (jj - 4));
          float u = su[n], w = sw[n], s = ss[n];
          const float al = pal[n], be = pbe[n], av = pav[n], bv = pbv[n], om = pom[n];
#pragma unroll
          for (int rr = 0; rr < 4; ++rr) {
            // cur = Wx at (t_local = 4p+rr, col n); static acc indices
            const float cur = (p < 16) ? acc[rr][jj] : acc[4 + rr][jj];
            // numpy left-to-right, each op individually rounded (no FMA contraction)
            w = __fadd_rn(__fadd_rn(__fmul_rn(be, w), __fmul_rn(av, u)), __fmul_rn(bv, s));
            u = __fadd_rn(__fmul_rn(al, __fsub_rn(u, s)), __fmul_rn(om, __fsub_rn(cur, w)));
            s = (u > 1.0f) ? 1.0f : 0.0f;
            if (jj < 4) spkA[rr][jj] = s;
            else spkB[rr][jj - 4] = s;
          }
          su[n] = u; sw[n] = w; ss[n] = s;
        }
        // coalesced spike stores: t = b*T + tt*128 + 4p + rr
#pragma unroll
        for (int rr = 0; rr < 4; ++rr) {
          const size_t trow = ((size_t)b * T_SZ + tt * 128 + 4 * p + rr) * H_SZ + N0;
          if constexpr (!ISB) {
            f32x4 v0 = {spkA[rr][0], spkA[rr][1], spkA[rr][2], spkA[rr][3]};
            f32x4 v1 = {spkB[rr][0], spkB[rr][1], spkB[rr][2], spkB[rr][3]};
            *reinterpret_cast<f32x4*>(outf + trow + tx * 4) = v0;
            *reinterpret_cast<f32x4*>(outf + trow + 64 + tx * 4) = v1;
          } else {
            // pack 4 bf16 (1.0f->0x3F80, 0.0f->0 exact by truncation)
            uint2 d0, d1;
            d0.x = (__float_as_uint(spkA[rr][1]) & 0xffff0000u) | (__float_as_uint(spkA[rr][0]) >> 16);
            d0.y = (__float_as_uint(spkA[rr][3]) & 0xffff0000u) | (__float_as_uint(spkA[rr][2]) >> 16);
            d1.x = (__float_as_uint(spkB[rr][1]) & 0xffff0000u) | (__float_as_uint(spkB[rr][0]) >> 16);
            d1.y = (__float_as_uint(spkB[rr][3]) & 0xffff0000u) | (__float_as_uint(spkB[rr][2]) >> 16);
            *reinterpret_cast<uint2*>(outu + (trow + tx * 4) / 2) = d0;
            *reinterpret_cast<uint2*>(outu + (trow + 64 + tx * 4) / 2) = d1;
          }
        }
      }
      __syncthreads();  // state handoff to next phase's ty group
    }
  }
}

__global__ __launch_bounds__(256) void adlif_fused(
    const void* __restrict__ X, const void* __restrict__ Wm,
    const void* __restrict__ alpha_p, const void* __restrict__ beta_p,
    const void* __restrict__ a_p, const void* __restrict__ b_p,
    const void* __restrict__ u0p, const void* __restrict__ w0p,
    const void* __restrict__ s0p, void* __restrict__ out) {
  __shared__ float As[16 * LSTR];  // 8.45 KB GEMM staging
  __shared__ float Bs[16 * LSTR];  // 8.45 KB
  __shared__ float st[8 * 128];    // 4 KB scan state + params
  if (detect_bf16(reinterpret_cast<const unsigned int*>(X)))
    fused_body<true>(X, Wm, alpha_p, beta_p, a_p, b_p, u0p, w0p, s0p, out, As, Bs, st);
  else
    fused_body<false>(X, Wm, alpha_p, beta_p, a_p, b_p, u0p, w0p, s0p, out, As, Bs, st);
}

extern "C" void kernel_launch(void* const* d_in, const int* in_sizes, int n_in,
                              void* d_out, int out_size, void* d_ws, size_t ws_size,
                              hipStream_t stream) {
  // single fused dispatch; d_ws unused (Wx never materialized)
  adlif_fused<<<dim3(B_SZ * 4), dim3(256), 0, stream>>>(
      d_in[0], d_in[1], d_in[2], d_in[3], d_in[4], d_in[5], d_in[6], d_in[7],
      d_in[8], d_out);
}

// Round 9
// 590.953 us; speedup vs baseline: 1.1694x; 1.1655x over previous
//
#include <hip/hip_runtime.h>
#include <hip/hip_bf16.h>

// adLIF FUSED v2: one kernel computes Wx = x@W^T tile-by-tile (r6 fp32 FMA GEMM
// body VERBATIM -> bit-exact k-order) and scans each tile's 128 timesteps via a
// 16 KB LDS transpose buffer. Wx never touches HBM (saves 268 MB round-trip +
// the latency-bound standalone scan kernel, r0-r17 evidence).
// r18 lesson: phase design had 16/256 threads active x 128 barriers/block ->
//   +122 us dispatch overhead. v2: 4 sub-phases/tile (8 barriers), owners dump
//   acc rows to LDS wxs[32][128], then 128 threads scan ONE column each with
//   u/w/s/params in REGISTERS for the whole kernel (no LDS state). Scan reads
//   are recurrence-independent -> compiler hoists/pipelines ds_reads; 2
//   lanes/bank = conflict-free. All branches wave-uniform.
// Block = (b, 128-h strip): 512 blocks, 33.3 KB LDS, ~2 blocks/CU.
// Input dtype (fp32 vs bf16) detected on device from x's bit pattern.

#define M_SZ 65536  // B*T
#define H_SZ 512
#define K_SZ 512
#define B_SZ 128
#define T_SZ 512
#define LSTR 132  // LDS row stride (dwords), %32==4: staging writes conflict-free

typedef __attribute__((ext_vector_type(4))) float f32x4;

__device__ __forceinline__ bool detect_bf16(const unsigned int* __restrict__ w) {
  int c = 0;
#pragma unroll
  for (int i = 0; i < 64; ++i) {
    unsigned int e = (w[i] >> 7) & 0xffu;
    c += (e >= 115u && e <= 131u) ? 1 : 0;
  }
  return c > 32;  // bf16 exponents cluster in [115,131]; fp32 mantissa bits don't
}

template <bool ISB>
__device__ __forceinline__ f32x4 ld4t(const void* __restrict__ p, size_t off) {
  if constexpr (!ISB) {
    return *reinterpret_cast<const f32x4*>(reinterpret_cast<const float*>(p) + off);
  } else {
    uint2 v = *reinterpret_cast<const uint2*>(reinterpret_cast<const unsigned short*>(p) + off);
    f32x4 r;
    r.x = __uint_as_float((v.x & 0xffffu) << 16);
    r.y = __uint_as_float(v.x & 0xffff0000u);
    r.z = __uint_as_float((v.y & 0xffffu) << 16);
    r.w = __uint_as_float(v.y & 0xffff0000u);
    return r;
  }
}

template <bool ISB>
__device__ __forceinline__ float ld1t(const void* __restrict__ p, int i) {
  if constexpr (!ISB) return reinterpret_cast<const float*>(p)[i];
  return __uint_as_float((unsigned int)(reinterpret_cast<const unsigned short*>(p)[i]) << 16);
}

// ---------------- fused GEMM + scan body ------------------------------------
template <bool ISB>
__device__ __forceinline__ void fused_body(
    const void* __restrict__ X, const void* __restrict__ Wm,
    const void* __restrict__ alpha_p, const void* __restrict__ beta_p,
    const void* __restrict__ a_p, const void* __restrict__ b_p,
    const void* __restrict__ u0p, const void* __restrict__ w0p,
    const void* __restrict__ s0p, void* __restrict__ out,
    float* __restrict__ As, float* __restrict__ Bs, float* __restrict__ wxs) {
  const int tid = threadIdx.x;
  const int r0 = tid >> 2;       // 0..63: staged row
  const int q0 = (tid & 3) * 4;  // 0,4,8,12: k-group
  const int tx = tid & 15;       // n-group
  const int ty = tid >> 4;       // m-group
  const int b = blockIdx.x >> 2;
  const int N0 = (blockIdx.x & 3) * 128;

  // ---- scan state: REGISTERS, thread tid<128 owns column n=tid (h=N0+tid)
  // for the entire kernel. Only read/written under wave-uniform tid<128.
  float al = 0.f, be = 0.f, av = 0.f, bv = 0.f, om = 0.f, u = 0.f, w = 0.f, s = 0.f;
  if (tid < 128) {
    const int h = N0 + tid;
    al = fminf(fmaxf(ld1t<ISB>(alpha_p, h), (float)0.8187307530779818),
               (float)0.9607894391523232);
    be = fminf(fmaxf(ld1t<ISB>(beta_p, h), (float)0.9672161004820059),
               (float)0.9917013044213351);
    av = fminf(fmaxf(ld1t<ISB>(a_p, h), -1.0f), 1.0f);
    bv = fminf(fmaxf(ld1t<ISB>(b_p, h), 0.0f), 2.0f);
    om = __fsub_rn(1.0f, al);
    const int bh = b * H_SZ + h;
    u = ld1t<ISB>(u0p, bh);
    w = ld1t<ISB>(w0p, bh);
    s = ld1t<ISB>(s0p, bh);
  }

  float* outf = reinterpret_cast<float*>(out);
  unsigned short* outu = reinterpret_cast<unsigned short*>(out);

  for (int tt = 0; tt < 4; ++tt) {  // M-tile = 128 consecutive t of batch b
    const size_t M0 = (size_t)b * T_SZ + tt * 128;

    float acc[8][8];
#pragma unroll
    for (int i = 0; i < 8; ++i)
#pragma unroll
      for (int j = 0; j < 8; ++j) acc[i][j] = 0.0f;

    const size_t aoff0 = (M0 + r0) * K_SZ + q0;
    const size_t aoff1 = (M0 + r0 + 64) * K_SZ + q0;
    const size_t boff0 = (size_t)(N0 + r0) * K_SZ + q0;
    const size_t boff1 = (size_t)(N0 + r0 + 64) * K_SZ + q0;

    f32x4 pa0 = ld4t<ISB>(X, aoff0), pa1 = ld4t<ISB>(X, aoff1);
    f32x4 pb0 = ld4t<ISB>(Wm, boff0), pb1 = ld4t<ISB>(Wm, boff1);

    for (int kk = 0; kk < K_SZ; kk += 16) {  // r6 k-loop VERBATIM
      __syncthreads();  // prior compute done -> LDS free
      As[(q0 + 0) * LSTR + r0] = pa0.x; As[(q0 + 1) * LSTR + r0] = pa0.y;
      As[(q0 + 2) * LSTR + r0] = pa0.z; As[(q0 + 3) * LSTR + r0] = pa0.w;
      As[(q0 + 0) * LSTR + r0 + 64] = pa1.x; As[(q0 + 1) * LSTR + r0 + 64] = pa1.y;
      As[(q0 + 2) * LSTR + r0 + 64] = pa1.z; As[(q0 + 3) * LSTR + r0 + 64] = pa1.w;
      Bs[(q0 + 0) * LSTR + r0] = pb0.x; Bs[(q0 + 1) * LSTR + r0] = pb0.y;
      Bs[(q0 + 2) * LSTR + r0] = pb0.z; Bs[(q0 + 3) * LSTR + r0] = pb0.w;
      Bs[(q0 + 0) * LSTR + r0 + 64] = pb1.x; Bs[(q0 + 1) * LSTR + r0 + 64] = pb1.y;
      Bs[(q0 + 2) * LSTR + r0 + 64] = pb1.z; Bs[(q0 + 3) * LSTR + r0 + 64] = pb1.w;
      __syncthreads();  // tile ready
      if (kk + 16 < K_SZ) {
        pa0 = ld4t<ISB>(X, aoff0 + kk + 16); pa1 = ld4t<ISB>(X, aoff1 + kk + 16);
        pb0 = ld4t<ISB>(Wm, boff0 + kk + 16); pb1 = ld4t<ISB>(Wm, boff1 + kk + 16);
      }
#pragma unroll
      for (int k = 0; k < 16; ++k) {
        const f32x4 a0 = *reinterpret_cast<const f32x4*>(As + k * LSTR + ty * 4);
        const f32x4 a1 = *reinterpret_cast<const f32x4*>(As + k * LSTR + 64 + ty * 4);
        const f32x4 b0 = *reinterpret_cast<const f32x4*>(Bs + k * LSTR + tx * 4);
        const f32x4 b1 = *reinterpret_cast<const f32x4*>(Bs + k * LSTR + 64 + tx * 4);
        const float avv[8] = {a0.x, a0.y, a0.z, a0.w, a1.x, a1.y, a1.z, a1.w};
        const float bvv[8] = {b0.x, b0.y, b0.z, b0.w, b1.x, b1.y, b1.z, b1.w};
#pragma unroll
        for (int i = 0; i < 8; ++i)
#pragma unroll
          for (int j = 0; j < 8; ++j) acc[i][j] += avv[i] * bvv[j];  // contracts to FMA
      }
    }
    // acc[r][j] = Wx[t_local = (r<4 ? ty*4+r : 64+ty*4+(r-4))][n = (j<4 ?
    // tx*4+j : 64+tx*4+(j-4))]. Scan in 4 subs of 32 t:
    //   sub0: ty 0..7  rows 0..3 (t 0..31)    sub1: ty 8..15 rows 0..3 (32..63)
    //   sub2: ty 0..7  rows 4..7 (64..95)     sub3: ty 8..15 rows 4..7 (96..127)
#pragma unroll
    for (int sub = 0; sub < 4; ++sub) {
      __syncthreads();  // prior sub's (or prior tile's) wxs reads complete
      const bool owner = (sub & 1) ? (ty >= 8) : (ty < 8);  // wave-uniform
      if (owner) {
#pragma unroll
        for (int rr = 0; rr < 4; ++rr) {
          const int row = (ty & 7) * 4 + rr;          // t within sub
          const int r = (sub < 2) ? rr : 4 + rr;      // static acc row
          f32x4 v0 = {acc[r][0], acc[r][1], acc[r][2], acc[r][3]};
          f32x4 v1 = {acc[r][4], acc[r][5], acc[r][6], acc[r][7]};
          *reinterpret_cast<f32x4*>(wxs + row * 128 + tx * 4) = v0;
          *reinterpret_cast<f32x4*>(wxs + row * 128 + 64 + tx * 4) = v1;
        }
      }
      __syncthreads();  // wxs[32][128] ready
      if (tid < 128) {  // wave-uniform: waves 0-1 scan, each thread one column
        const size_t tbase =
            ((size_t)b * T_SZ + tt * 128 + sub * 32) * H_SZ + N0 + tid;
#pragma unroll
        for (int t = 0; t < 32; ++t) {
          const float cur = wxs[t * 128 + tid];  // independent of recurrence
          // numpy left-to-right, each op individually rounded (no FMA contraction)
          w = __fadd_rn(__fadd_rn(__fmul_rn(be, w), __fmul_rn(av, u)), __fmul_rn(bv, s));
          u = __fadd_rn(__fmul_rn(al, __fsub_rn(u, s)), __fmul_rn(om, __fsub_rn(cur, w)));
          const bool sp = (u > 1.0f);
          s = sp ? 1.0f : 0.0f;
          if constexpr (ISB)
            outu[tbase + (size_t)t * H_SZ] = sp ? (unsigned short)0x3F80u : (unsigned short)0u;
          else
            outf[tbase + (size_t)t * H_SZ] = s;
        }
      }
    }
  }
}

__global__ __launch_bounds__(256) void adlif_fused(
    const void* __restrict__ X, const void* __restrict__ Wm,
    const void* __restrict__ alpha_p, const void* __restrict__ beta_p,
    const void* __restrict__ a_p, const void* __restrict__ b_p,
    const void* __restrict__ u0p, const void* __restrict__ w0p,
    const void* __restrict__ s0p, void* __restrict__ out) {
  __shared__ float As[16 * LSTR];   // 8.45 KB GEMM staging
  __shared__ float Bs[16 * LSTR];   // 8.45 KB
  __shared__ float wxs[32 * 128];   // 16 KB Wx transpose buffer (one 32-t sub)
  if (detect_bf16(reinterpret_cast<const unsigned int*>(X)))
    fused_body<true>(X, Wm, alpha_p, beta_p, a_p, b_p, u0p, w0p, s0p, out, As, Bs, wxs);
  else
    fused_body<false>(X, Wm, alpha_p, beta_p, a_p, b_p, u0p, w0p, s0p, out, As, Bs, wxs);
}

extern "C" void kernel_launch(void* const* d_in, const int* in_sizes, int n_in,
                              void* d_out, int out_size, void* d_ws, size_t ws_size,
                              hipStream_t stream) {
  // single fused dispatch; d_ws unused (Wx never materialized in HBM)
  adlif_fused<<<dim3(B_SZ * 4), dim3(256), 0, stream>>>(
      d_in[0], d_in[1], d_in[2], d_in[3], d_in[4], d_in[5], d_in[6], d_in[7],
      d_in[8], d_out);
}